// Round 16
// baseline (106.614 us; speedup 1.0000x reference)
//
#include <hip/hip_runtime.h>
#include <math.h>

typedef __attribute__((ext_vector_type(8))) short short8;
typedef __attribute__((ext_vector_type(4))) float f32x4;
typedef __attribute__((ext_vector_type(4))) unsigned short us4v;

__device__ __forceinline__ unsigned short f2bf(float f) {
    unsigned u = __float_as_uint(f);
    return (unsigned short)((u + 0x7FFFu + ((u >> 16) & 1u)) >> 16);
}
// HW packed f32->bf16 (RNE, same as f2bf): 2 elems in 1 instr; low16 = first arg
__device__ __forceinline__ unsigned cvtpk(float lo, float hi) {
    unsigned r;
    asm("v_cvt_pk_bf16_f32 %0, %1, %2" : "=v"(r) : "v"(lo), "v"(hi));
    return r;
}
__device__ __forceinline__ unsigned short f2bf1(float v) {
    return (unsigned short)(cvtpk(v, 0.f) & 0xffffu);
}
// max with lane (c <-> c+8) partner via DPP row_ror:8 — VALU-only, no LDS pipe
__device__ __forceinline__ float fmax_x8(float v) {
    int s = __builtin_amdgcn_mov_dpp(__float_as_int(v), 0x128, 0xf, 0xf, true);
    return fmaxf(v, __int_as_float(s));
}

#define C1T_SS 3464  // conv1 img LDS elems per sample (96 rows x 36 + 8 tail)
#define C1_RS 36     // conv1 img LDS row stride (32 data + 4 pad)
#define P1R 1176     // p1 record per sample: 84 rows x 14 (stride 14)
#define P2S 424      // fc activation tile row stride
#define A1S 136
#define A2S 104

// Fully fused LeNet, 8 samples/block, 4 blocks/CU (LDS 32.7KB, VGPR<=128).
// conv1: 4 x 2-sample subtiles (R14 structure), wf1[5][2] + in-register A0/A2
// shifted fragments (R10/R11-verified; -40 VGPR vs wf1[5][4]).
// conv2: R13-verified yo-packed mapping (M=smp(c>>1)|yo(c&1) fills 16 rows
// with 8 samples; pool in-lane) -> pkbuf -> LDS fc tile (R14 path).
// fc1/2/3 in-kernel; A-rows 8..15 read stale-finite LDS, discarded by guards.
__global__ __launch_bounds__(256, 4) void conv12fc_mfma(
    const float* __restrict__ x,
    const unsigned short* __restrict__ c1wf, const float* __restrict__ c1b,
    const unsigned short* __restrict__ c2wf, const float* __restrict__ c2b,
    const unsigned short* __restrict__ wb1, const float* __restrict__ f1b,
    const unsigned short* __restrict__ wb2, const float* __restrict__ f2b,
    const unsigned short* __restrict__ wb3, const float* __restrict__ f3b,
    float* __restrict__ emb, float* __restrict__ part)
{
    __shared__ __align__(16) unsigned short img[2 * C1T_SS];   // 13856 B
    __shared__ __align__(16) unsigned short p1s[8 * P1R + 16]; // 18848 B
    __shared__ float rsum[4];
    const int t = threadIdx.x;
    const int lane = t & 63, w = t >> 6;
    const int grp = lane >> 4, c = lane & 15;
    const int smp = c >> 3, q = c & 7;

    // zero img row pads (2x96 rows, elems 32..35) + sample tails + p1s tail pad
    if (t < 192) {
        int s = t / 96, rr = t - s * 96;
        *(uint2*)&img[s * C1T_SS + rr * C1_RS + 32] = make_uint2(0u, 0u);
    }
    if (t < 2) {
        *(uint4*)&img[t * C1T_SS + 3456] = make_uint4(0u, 0u, 0u, 0u);
        *(uint4*)&p1s[8 * P1R + t * 8] = make_uint4(0u, 0u, 0u, 0u);
    }

    // conv1 weight fragments: 2 x-parities (A-shift covers the other two)
    short8 wf1[5][2];
#pragma unroll
    for (int s = 0; s < 5; s++)
#pragma unroll
        for (int off = 0; off < 2; off++)
            wf1[s][off] = *(const short8*)&c1wf[(((s * 4 + off) * 4 + grp) * 16 + c) * 8];
    int ciA[5], kpA[5];
#pragma unroll
    for (int s = 0; s < 5; s++) {
        int b = s * 4 + grp; if (b > 17) b = 17;   // clamped dup has zero weights
        ciA[s] = b / 6; kpA[s] = b % 6;
    }
    const float bias1 = (c < 6) ? c1b[c] : 0.f;

    const float4* xs4 = (const float4*)(x + (size_t)blockIdx.x * 24576);
    float4 r[6];

    // prologue: load subtile 0 (2 samples = 1536 float4)
#pragma unroll
    for (int k = 0; k < 6; k++) r[k] = xs4[k * 256 + t];

    for (int st = 0; st < 4; st++) {
        // convert + ds_write current subtile (1x per element, cvt_pk)
#pragma unroll
        for (int k = 0; k < 6; k++) {
            int f = k * 256 + t;                  // 0..1535
            int s = (f >= 768) ? 1 : 0;
            int w4 = f - s * 768;
            int ci = w4 >> 8, rem = w4 & 255, y = rem >> 3, xq = rem & 7;
            uint2 pk = make_uint2(cvtpk(r[k].x, r[k].y), cvtpk(r[k].z, r[k].w));
            *(uint2*)&img[s * C1T_SS + (ci * 32 + y) * C1_RS + xq * 4] = pk;
        }
        __syncthreads();

        // issue next subtile's loads (fly under this subtile's compute)
        if (st < 3) {
#pragma unroll
            for (int k = 0; k < 6; k++) r[k] = xs4[(st + 1) * 1536 + k * 256 + t];
        }

        // conv1 compute: 14 py items over 4 waves (A0/A2 from one row window)
        for (int py = w; py < 14; py += 4) {
            f32x4 a00 = {0.f,0.f,0.f,0.f}, a01 = a00, a10 = a00, a11 = a00;
#pragma unroll
            for (int s = 0; s < 5; s++) {
                int e = smp * C1T_SS + (ciA[s] * 32 + py * 2 + kpA[s]) * C1_RS + q * 4;
                us4v h0 = *(const us4v*)&img[e];
                us4v h1 = *(const us4v*)&img[e + 4];
                ushort2 h2 = *(const ushort2*)&img[e + 8];
                short8 A0 = { (short)h0[0],(short)h0[1],(short)h0[2],(short)h0[3],
                              (short)h1[0],(short)h1[1],(short)h1[2],(short)h1[3] };
                short8 A2 = { (short)h0[2],(short)h0[3],(short)h1[0],(short)h1[1],
                              (short)h1[2],(short)h1[3],(short)h2.x,(short)h2.y };
                a00 = __builtin_amdgcn_mfma_f32_16x16x32_bf16(A0, wf1[s][0], a00, 0, 0, 0);
                a01 = __builtin_amdgcn_mfma_f32_16x16x32_bf16(A0, wf1[s][1], a01, 0, 0, 0);
                a10 = __builtin_amdgcn_mfma_f32_16x16x32_bf16(A2, wf1[s][0], a10, 0, 0, 0);
                a11 = __builtin_amdgcn_mfma_f32_16x16x32_bf16(A2, wf1[s][1], a11, 0, 0, 0);
            }
            // pool x-pairs in-lane, y-pair across lane c <-> c+8 (DPP, no LDS)
            f32x4 pe2, po2;
#pragma unroll
            for (int i = 0; i < 4; i++) {
                pe2[i] = fmax_x8(fmaxf(a00[i], a01[i]));
                po2[i] = fmax_x8(fmaxf(a10[i], a11[i]));
            }
            if (c < 6) {
#pragma unroll
                for (int i = 0; i < 4; i++) {
                    int m = grp * 4 + i;           // D row: sample = m>>3, quad = m&7
                    int qo = m & 7;
                    if (qo < 7) {
                        int sm = m >> 3;
                        float v0 = fmaxf(pe2[i] + bias1, 0.f);
                        float v1 = fmaxf(po2[i] + bias1, 0.f);
                        *(unsigned*)&p1s[(2 * st + sm) * P1R + (c * 14 + py) * 14 + qo * 2]
                            = cvtpk(v0, v1);
                    }
                }
            }
        }
        __syncthreads();   // img reads done before next convert; p1s subtile written
    }

    // ---- conv2 phase: 8 samples, yo packed into M (R13-verified mapping) ----
    short8 wf2[8][2];
#pragma unroll
    for (int s = 0; s < 8; s++)
#pragma unroll
        for (int off = 0; off < 2; off++)
            wf2[s][off] = *(const short8*)&c2wf[(((s * 2 + off) * 4 + grp) * 16 + c) * 8];
    int ciB[8], kyB[8];
#pragma unroll
    for (int s = 0; s < 8; s++) {
        int b = s * 4 + grp; if (b > 29) b = 29;   // clamped dup has zero weights
        ciB[s] = b / 5; kyB[s] = b % 5;
    }
    const float bias2 = c2b[c];
    const int arow2 = (c >> 1) * P1R;   // A row: smp = c>>1, yo = c&1
    const int yoff = c & 1;

    // conv2 compute -> per-lane register buffer (statically indexed)
    unsigned pkbuf[7];
#pragma unroll
    for (int j = 0; j < 7; j++) {
        const int item = w + j * 4;
        if (item < 25) {
            const int py = item / 5, px = item % 5;
            f32x4 a0 = {0.f,0.f,0.f,0.f}, a1 = a0;
#pragma unroll
            for (int s = 0; s < 8; s++) {
                int e = arow2 + (ciB[s] * 14 + py * 2 + yoff + kyB[s]) * 14 + px * 2;
                union { unsigned u[4]; short8 v; } af;
                af.u[0] = *(const unsigned*)&p1s[e];
                af.u[1] = *(const unsigned*)&p1s[e + 2];
                af.u[2] = *(const unsigned*)&p1s[e + 4];
                af.u[3] = *(const unsigned*)&p1s[e + 6];
                a0 = __builtin_amdgcn_mfma_f32_16x16x32_bf16(af.v, wf2[s][0], a0, 0, 0, 0);
                a1 = __builtin_amdgcn_mfma_f32_16x16x32_bf16(af.v, wf2[s][1], a1, 0, 0, 0);
            }
            // pool: yo in-lane (acc pairs), px-parity across a0/a1
            float v0 = fmaxf(fmaxf(fmaxf(a0[0], a0[1]), fmaxf(a1[0], a1[1])) + bias2, 0.f);
            float v1 = fmaxf(fmaxf(fmaxf(a0[2], a0[3]), fmaxf(a1[2], a1[3])) + bias2, 0.f);
            pkbuf[j] = cvtpk(v0, v1);   // lo = smp grp*2, hi = smp grp*2+1
        }
    }
    __syncthreads();   // all p1s reads complete -> safe to overlay fc tile

    // scatter into fc activation tile [8][424] (overlaid on p1s) + zero K-pads
    unsigned short* p2t = p1s;
#pragma unroll
    for (int j = 0; j < 7; j++) {
        const int item = w + j * 4;
        if (item < 25) {
            p2t[(grp * 2 + 0) * P2S + c * 25 + item] = (unsigned short)(pkbuf[j] & 0xffffu);
            p2t[(grp * 2 + 1) * P2S + c * 25 + item] = (unsigned short)(pkbuf[j] >> 16);
        }
    }
    if (t < 32) {
        int s = t >> 1, h = t & 1;   // zero K-pads for all 16 A-rows
        *(uint4*)&p2t[s * P2S + 400 + h * 8] = make_uint4(0u, 0u, 0u, 0u);
    }
    __syncthreads();

    // ---- fc1: 400->120 (K=416, 13 steps), wave w takes N-tiles w, w+4 ----
    unsigned short* a1s = img;              // img dead; reads to row 15 stay in img
    unsigned short* a2s = img + 16 * A1S;
    {
        f32x4 acc[2] = {{0.f,0.f,0.f,0.f},{0.f,0.f,0.f,0.f}};
        const int sb = c * P2S;             // rows 8..15 = stale finite, discarded
#pragma unroll
        for (int ks = 0; ks < 13; ks++) {
            short8 a = *(const short8*)&p2t[sb + ks * 32 + grp * 8];
#pragma unroll
            for (int j = 0; j < 2; j++) {
                int o = (w + 4 * j) * 16 + c;
                short8 b = *(const short8*)&wb1[o * 416 + ks * 32 + grp * 8];
                acc[j] = __builtin_amdgcn_mfma_f32_16x16x32_bf16(a, b, acc[j], 0, 0, 0);
            }
        }
        __syncthreads();
#pragma unroll
        for (int j = 0; j < 2; j++) {
            int o = (w + 4 * j) * 16 + c;
            float bias = (o < 120) ? f1b[o] : 0.f;
#pragma unroll
            for (int i = 0; i < 4; i++) {
                int s = grp * 4 + i;
                if (s < 8) a1s[s * A1S + o] = f2bf1(fmaxf(acc[j][i] + bias, 0.f));
            }
        }
    }
    __syncthreads();

    // ---- fc2: 120->84 (K=128, 4 steps), wave w takes N-tiles w (+4 if w<2) ----
    {
        f32x4 acc[2] = {{0.f,0.f,0.f,0.f},{0.f,0.f,0.f,0.f}};
        const int sb = c * A1S;
#pragma unroll
        for (int ks = 0; ks < 4; ks++) {
            short8 a = *(const short8*)&a1s[sb + ks * 32 + grp * 8];
#pragma unroll
            for (int j = 0; j < 2; j++) {
                int nt = w + 4 * j;
                if (nt < 6) {
                    int o = nt * 16 + c;
                    short8 b = *(const short8*)&wb2[o * 128 + ks * 32 + grp * 8];
                    acc[j] = __builtin_amdgcn_mfma_f32_16x16x32_bf16(a, b, acc[j], 0, 0, 0);
                }
            }
        }
        __syncthreads();
#pragma unroll
        for (int j = 0; j < 2; j++) {
            int nt = w + 4 * j;
            if (nt < 6) {
                int o = nt * 16 + c;
                float bias = (o < 84) ? f2b[o] : 0.f;
#pragma unroll
                for (int i = 0; i < 4; i++) {
                    int s = grp * 4 + i;
                    if (s < 8) a2s[s * A2S + o] = f2bf1(fmaxf(acc[j][i] + bias, 0.f));
                }
            }
        }
    }
    __syncthreads();

    // ---- fc3: 84->64 (K=96, 3 steps), N-tile = w; emb + fused psum ----
    {
        f32x4 acc = {0.f,0.f,0.f,0.f};
        const int sb = c * A2S;
        const int o = w * 16 + c;
#pragma unroll
        for (int ks = 0; ks < 3; ks++) {
            short8 a = *(const short8*)&a2s[sb + ks * 32 + grp * 8];
            short8 b = *(const short8*)&wb3[o * 96 + ks * 32 + grp * 8];
            acc = __builtin_amdgcn_mfma_f32_16x16x32_bf16(a, b, acc, 0, 0, 0);
        }
        const float bias = f3b[o];
        float psum = 0.f;
#pragma unroll
        for (int i = 0; i < 4; i++) {
            int s = grp * 4 + i;
            if (s < 8) {
                float v = acc[i] + bias;
                emb[((size_t)blockIdx.x * 8 + s) * 64 + o] = v;
                psum += v;
            }
        }
#pragma unroll
        for (int off = 32; off; off >>= 1) psum += __shfl_xor(psum, off);
        if (lane == 0) rsum[w] = psum;
        __syncthreads();
        if (t == 0) part[blockIdx.x] = (rsum[0] + rsum[1]) + (rsum[2] + rsum[3]);
    }
}

// one-shot conversion: FC weights to padded bf16 tiles + conv weight fragments
__global__ __launch_bounds__(256) void prep_weights(
    const float* __restrict__ c1w, const float* __restrict__ c2w,
    const float* __restrict__ f1w, const float* __restrict__ f2w,
    const float* __restrict__ f3w,
    unsigned short* __restrict__ wb1, unsigned short* __restrict__ wb2,
    unsigned short* __restrict__ wb3,
    unsigned short* __restrict__ c1wf, unsigned short* __restrict__ c2wf)
{
    const int t0 = blockIdx.x * 256 + threadIdx.x;
    const int stride = gridDim.x * 256;
    for (int i = t0; i < 128 * 416; i += stride) {
        int o = i / 416, k = i % 416;
        wb1[i] = f2bf((o < 120 && k < 400) ? f1w[o * 400 + k] : 0.f);
    }
    for (int i = t0; i < 96 * 128; i += stride) {
        int o = i / 128, k = i % 128;
        wb2[i] = f2bf((o < 84 && k < 120) ? f2w[o * 120 + k] : 0.f);
    }
    for (int i = t0; i < 64 * 96; i += stride) {
        int o = i / 96, k = i % 96;
        wb3[i] = f2bf((k < 84) ? f3w[o * 84 + k] : 0.f);
    }
    // c1wf[s(5)][off(4)][grp(4)][c(16)][j(8)]
    for (int i = t0; i < 10240; i += stride) {
        int j = i & 7, c = (i >> 3) & 15, grp = (i >> 7) & 3;
        int off = (i >> 9) & 3, s = i >> 11;
        int b = s * 4 + grp;
        int ci = b / 6, kp = b % 6;
        int kx = j - off;
        float v = 0.f;
        if (b < 18 && kx >= 0 && kx <= 4) {
            if (c < 6 && kp <= 4)
                v = c1w[c * 75 + ci * 25 + kp * 5 + kx];
            else if (c >= 8 && c < 14 && kp >= 1)
                v = c1w[(c - 8) * 75 + ci * 25 + (kp - 1) * 5 + kx];
        }
        c1wf[i] = f2bf(v);
    }
    // c2wf[s(8)][off(2)][grp(4)][c(16)][j(8)]
    for (int i = t0; i < 8192; i += stride) {
        int j = i & 7, c = (i >> 3) & 15, grp = (i >> 7) & 3;
        int off = (i >> 9) & 1, s = i >> 10;
        int b = s * 4 + grp;
        int kx = j - off;
        float v = 0.f;
        if (b < 30 && kx >= 0 && kx <= 4) {
            int ci = b / 5, ky = b % 5;
            v = c2w[c * 150 + ci * 25 + ky * 5 + kx];
        }
        c2wf[i] = f2bf(v);
    }
}

// per-row softmax + |softmax - proto|; proto re-reduced per block from the
// 2560 partials (fixed order -> deterministic, identical in every block)
__global__ __launch_bounds__(256) void softmax_abs(float* __restrict__ io,
                                                   const float* __restrict__ part) {
    const int lane = threadIdx.x & 63;
    const int row = (blockIdx.x << 2) + (threadIdx.x >> 6);
    float e = io[(size_t)row * 64 + lane];   // issue early, independent of reduce
    float ps = 0.f;
#pragma unroll
    for (int k = 0; k < 40; k++) ps += part[k * 64 + lane];
#pragma unroll
    for (int off = 32; off; off >>= 1) ps += __shfl_xor(ps, off);
    const float proto = ps / 5.0f;
    float m = e;
#pragma unroll
    for (int off = 32; off; off >>= 1) m = fmaxf(m, __shfl_xor(m, off));
    float p = expf(e - m);
    float s = p;
#pragma unroll
    for (int off = 32; off; off >>= 1) s += __shfl_xor(s, off);
    io[(size_t)row * 64 + lane] = fabsf(p / s - proto);
}

extern "C" void kernel_launch(void* const* d_in, const int* in_sizes, int n_in,
                              void* d_out, int out_size, void* d_ws, size_t ws_size,
                              hipStream_t stream) {
    const float* x   = (const float*)d_in[0];
    const float* c1w = (const float*)d_in[1];
    const float* c1b = (const float*)d_in[2];
    const float* c2w = (const float*)d_in[3];
    const float* c2b = (const float*)d_in[4];
    const float* f1w = (const float*)d_in[5];
    const float* f1b = (const float*)d_in[6];
    const float* f2w = (const float*)d_in[7];
    const float* f2b = (const float*)d_in[8];
    const float* f3w = (const float*)d_in[9];
    const float* f3b = (const float*)d_in[10];
    float* out = (float*)d_out;

    const int N = in_sizes[0] / 3072;                 // 20480
    float* part = (float*)d_ws;                       // N/8 = 2560 floats
    unsigned short* wb1  = (unsigned short*)((char*)d_ws + 16384); // 128x416
    unsigned short* wb2  = wb1 + 128 * 416;                        // 96x128
    unsigned short* wb3  = wb2 + 96 * 128;                         // 64x96
    unsigned short* c1wf = wb3 + 64 * 96;                          // 10240
    unsigned short* c2wf = c1wf + 10240;                           // 8192

    prep_weights<<<64, 256, 0, stream>>>(c1w, c2w, f1w, f2w, f3w,
                                         wb1, wb2, wb3, c1wf, c2wf);
    conv12fc_mfma<<<N / 8, 256, 0, stream>>>(x, c1wf, c1b, c2wf, c2b,
                                             wb1, f1b, wb2, f2b, wb3, f3b,
                                             out, part);
    softmax_abs<<<N / 4, 256, 0, stream>>>(out, part);
}

// Round 17
// 104.719 us; speedup vs baseline: 1.0181x; 1.0181x over previous
//
#include <hip/hip_runtime.h>
#include <math.h>

typedef __attribute__((ext_vector_type(8))) short short8;
typedef __attribute__((ext_vector_type(4))) float f32x4;
typedef __attribute__((ext_vector_type(4))) unsigned short us4v;

__device__ __forceinline__ unsigned short f2bf(float f) {
    unsigned u = __float_as_uint(f);
    return (unsigned short)((u + 0x7FFFu + ((u >> 16) & 1u)) >> 16);
}
// HW packed f32->bf16 (RNE, same as f2bf): 2 elems in 1 instr; low16 = first arg
__device__ __forceinline__ unsigned cvtpk(float lo, float hi) {
    unsigned r;
    asm("v_cvt_pk_bf16_f32 %0, %1, %2" : "=v"(r) : "v"(lo), "v"(hi));
    return r;
}
__device__ __forceinline__ unsigned short f2bf1(float v) {
    return (unsigned short)(cvtpk(v, 0.f) & 0xffffu);
}
// max with lane (c <-> c+8) partner via DPP row_ror:8 — VALU-only, no LDS pipe
__device__ __forceinline__ float fmax_x8(float v) {
    int s = __builtin_amdgcn_mov_dpp(__float_as_int(v), 0x128, 0xf, 0xf, true);
    return fmaxf(v, __int_as_float(s));
}

#define C1T_SS 3464  // conv1 img LDS elems per sample (96 rows x 36 + 8 tail)
#define C1_RS 36     // conv1 img LDS row stride (32 data + 4 pad)
#define P1R 1176     // p1 record per sample: 84 rows x 14 (stride 14)
#define P2S 424      // fc activation tile row stride (400 + 16 pad + bank spread)
#define A1S 136
#define A2S 104

// Fully fused conv1+pool -> conv2+pool -> fc1 -> fc2 -> fc3 -> emb + psum.
// 16 samples/block (R15 structure, measured best 94.6us). R17: removed two
// unneeded internal fc barriers (read/write regions disjoint: p2t=p1s region,
// a1s/a2s=img region) and added s_setprio(1) around MFMA clusters (T5).
__global__ __launch_bounds__(256, 3) void conv12fc_mfma(
    const float* __restrict__ x,
    const unsigned short* __restrict__ c1wf, const float* __restrict__ c1b,
    const unsigned short* __restrict__ c2wf, const float* __restrict__ c2b,
    const unsigned short* __restrict__ wb1, const float* __restrict__ f1b,
    const unsigned short* __restrict__ wb2, const float* __restrict__ f2b,
    const unsigned short* __restrict__ wb3, const float* __restrict__ f3b,
    float* __restrict__ emb, float* __restrict__ part)
{
    __shared__ __align__(16) unsigned short img[2 * C1T_SS];    // 13856 B
    __shared__ __align__(16) unsigned short p1s[16 * P1R + 16]; // 37664 B
    __shared__ float rsum[4];
    const int t = threadIdx.x;
    const int lane = t & 63, w = t >> 6;
    const int grp = lane >> 4, c = lane & 15;
    const int smp = c >> 3, q = c & 7;

    // zero img row pads (2x96 rows, elems 32..35) + sample tails + p1s tail pad
    if (t < 192) {
        int s = t / 96, rr = t - s * 96;
        *(uint2*)&img[s * C1T_SS + rr * C1_RS + 32] = make_uint2(0u, 0u);
    }
    if (t < 2) {
        *(uint4*)&img[t * C1T_SS + 3456] = make_uint4(0u, 0u, 0u, 0u);
        *(uint4*)&p1s[16 * P1R + t * 8] = make_uint4(0u, 0u, 0u, 0u);
    }

    // conv1 weight fragments: ALL 4 x-offset variants
    short8 wf1[5][4];
#pragma unroll
    for (int s = 0; s < 5; s++)
#pragma unroll
        for (int off = 0; off < 4; off++)
            wf1[s][off] = *(const short8*)&c1wf[(((s * 4 + off) * 4 + grp) * 16 + c) * 8];
    int ciA[5], kpA[5];
#pragma unroll
    for (int s = 0; s < 5; s++) {
        int b = s * 4 + grp; if (b > 17) b = 17;   // clamped dup has zero weights
        ciA[s] = b / 6; kpA[s] = b % 6;
    }
    const float bias1 = (c < 6) ? c1b[c] : 0.f;

    const float4* xs4 = (const float4*)(x + (size_t)blockIdx.x * 49152);
    float4 r[6];

    // prologue: load subtile 0 (2 samples = 1536 float4)
#pragma unroll
    for (int k = 0; k < 6; k++) r[k] = xs4[k * 256 + t];

    for (int st = 0; st < 8; st++) {
        // convert + ds_write current subtile (1x per element, cvt_pk)
#pragma unroll
        for (int k = 0; k < 6; k++) {
            int f = k * 256 + t;                  // 0..1535
            int s = (f >= 768) ? 1 : 0;
            int w4 = f - s * 768;
            int ci = w4 >> 8, rem = w4 & 255, y = rem >> 3, xq = rem & 7;
            uint2 pk = make_uint2(cvtpk(r[k].x, r[k].y), cvtpk(r[k].z, r[k].w));
            *(uint2*)&img[s * C1T_SS + (ci * 32 + y) * C1_RS + xq * 4] = pk;
        }
        __syncthreads();

        // issue next subtile's loads (fly under this subtile's compute)
        if (st < 7) {
#pragma unroll
            for (int k = 0; k < 6; k++) r[k] = xs4[(st + 1) * 1536 + k * 256 + t];
        }

        // conv1 compute: 14 py items over 4 waves
        for (int py = w; py < 14; py += 4) {
            f32x4 a00 = {0.f,0.f,0.f,0.f}, a01 = a00, a10 = a00, a11 = a00;
            __builtin_amdgcn_s_setprio(1);
#pragma unroll
            for (int s = 0; s < 5; s++) {
                int e = smp * C1T_SS + (ciA[s] * 32 + py * 2 + kpA[s]) * C1_RS + q * 4;
                union { us4v h[2]; short8 v; } af;
                af.h[0] = *(const us4v*)&img[e];
                af.h[1] = *(const us4v*)&img[e + 4];
                a00 = __builtin_amdgcn_mfma_f32_16x16x32_bf16(af.v, wf1[s][0], a00, 0, 0, 0);
                a01 = __builtin_amdgcn_mfma_f32_16x16x32_bf16(af.v, wf1[s][1], a01, 0, 0, 0);
                a10 = __builtin_amdgcn_mfma_f32_16x16x32_bf16(af.v, wf1[s][2], a10, 0, 0, 0);
                a11 = __builtin_amdgcn_mfma_f32_16x16x32_bf16(af.v, wf1[s][3], a11, 0, 0, 0);
            }
            __builtin_amdgcn_s_setprio(0);
            // pool x-pairs in-lane, y-pair across lane c <-> c+8 (DPP, no LDS)
            f32x4 pe2, po2;
#pragma unroll
            for (int i = 0; i < 4; i++) {
                pe2[i] = fmax_x8(fmaxf(a00[i], a01[i]));
                po2[i] = fmax_x8(fmaxf(a10[i], a11[i]));
            }
            if (c < 6) {
#pragma unroll
                for (int i = 0; i < 4; i++) {
                    int m = grp * 4 + i;           // D row: sample = m>>3, quad = m&7
                    int qo = m & 7;
                    if (qo < 7) {
                        int sm = m >> 3;
                        float v0 = fmaxf(pe2[i] + bias1, 0.f);
                        float v1 = fmaxf(po2[i] + bias1, 0.f);
                        *(unsigned*)&p1s[(2 * st + sm) * P1R + (c * 14 + py) * 14 + qo * 2]
                            = cvtpk(v0, v1);
                    }
                }
            }
        }
        __syncthreads();   // img reads done before next convert; p1s subtile written
    }

    // ---- conv2 phase (wf2 loaded after conv1 regs die) ----
    short8 wf2[8][2];
#pragma unroll
    for (int s = 0; s < 8; s++)
#pragma unroll
        for (int off = 0; off < 2; off++)
            wf2[s][off] = *(const short8*)&c2wf[(((s * 2 + off) * 4 + grp) * 16 + c) * 8];
    int ciB[8], kyB[8];
#pragma unroll
    for (int s = 0; s < 8; s++) {
        int b = s * 4 + grp; if (b > 29) b = 29;   // clamped dup has zero weights
        ciB[s] = b / 5; kyB[s] = b % 5;
    }
    const float bias2 = c2b[c];

    // conv2 compute -> per-lane register buffer (statically indexed)
    unsigned pkbuf[7][2];
#pragma unroll
    for (int j = 0; j < 7; j++) {
        const int item = w + j * 4;
        if (item < 25) {
            const int py = item / 5, px = item % 5;
            f32x4 a00 = {0.f,0.f,0.f,0.f}, a01 = a00, a10 = a00, a11 = a00;
            __builtin_amdgcn_s_setprio(1);
#pragma unroll
            for (int s = 0; s < 8; s++) {
                int rbase = ciB[s] * 14 + kyB[s] + py * 2;
#pragma unroll
                for (int yo = 0; yo < 2; yo++) {
                    int e = c * P1R + (rbase + yo) * 14 + px * 2;
                    union { unsigned u[4]; short8 v; } af;
                    af.u[0] = *(const unsigned*)&p1s[e];
                    af.u[1] = *(const unsigned*)&p1s[e + 2];
                    af.u[2] = *(const unsigned*)&p1s[e + 4];
                    af.u[3] = *(const unsigned*)&p1s[e + 6];
                    if (yo == 0) {
                        a00 = __builtin_amdgcn_mfma_f32_16x16x32_bf16(af.v, wf2[s][0], a00, 0, 0, 0);
                        a01 = __builtin_amdgcn_mfma_f32_16x16x32_bf16(af.v, wf2[s][1], a01, 0, 0, 0);
                    } else {
                        a10 = __builtin_amdgcn_mfma_f32_16x16x32_bf16(af.v, wf2[s][0], a10, 0, 0, 0);
                        a11 = __builtin_amdgcn_mfma_f32_16x16x32_bf16(af.v, wf2[s][1], a11, 0, 0, 0);
                    }
                }
            }
            __builtin_amdgcn_s_setprio(0);
            float v0 = fmaxf(fmaxf(fmaxf(a00[0], a01[0]), fmaxf(a10[0], a11[0])) + bias2, 0.f);
            float v1 = fmaxf(fmaxf(fmaxf(a00[1], a01[1]), fmaxf(a10[1], a11[1])) + bias2, 0.f);
            float v2 = fmaxf(fmaxf(fmaxf(a00[2], a01[2]), fmaxf(a10[2], a11[2])) + bias2, 0.f);
            float v3 = fmaxf(fmaxf(fmaxf(a00[3], a01[3]), fmaxf(a10[3], a11[3])) + bias2, 0.f);
            pkbuf[j][0] = cvtpk(v0, v1);
            pkbuf[j][1] = cvtpk(v2, v3);
        }
    }
    __syncthreads();   // all p1s reads complete -> safe to overlay fc tile

    // scatter into fc activation tile [16][424] (overlaid on p1s) + zero K-pad
    unsigned short* p2t = p1s;
#pragma unroll
    for (int j = 0; j < 7; j++) {
        const int item = w + j * 4;
        if (item < 25) {
#pragma unroll
            for (int i = 0; i < 4; i++) {
                unsigned v = pkbuf[j][i >> 1] >> ((i & 1) * 16);
                p2t[(grp * 4 + i) * P2S + c * 25 + item] = (unsigned short)v;
            }
        }
    }
    if (t < 32) {
        int s = t >> 1, h = t & 1;
        *(uint4*)&p2t[s * P2S + 400 + h * 8] = make_uint4(0u, 0u, 0u, 0u);
    }
    __syncthreads();

    // ---- fc1: 400->120 (K=416, 13 steps), N-tiles 0..7, wave w takes w, w+4 ----
    unsigned short* a1s = img;              // img is dead; 16x136 = 4352 B
    unsigned short* a2s = img + 16 * A1S;   // 16x104 = 3328 B
    {
        f32x4 acc[2] = {{0.f,0.f,0.f,0.f},{0.f,0.f,0.f,0.f}};
        const int sb = c * P2S;
        __builtin_amdgcn_s_setprio(1);
#pragma unroll
        for (int ks = 0; ks < 13; ks++) {
            short8 a = *(const short8*)&p2t[sb + ks * 32 + grp * 8];
#pragma unroll
            for (int j = 0; j < 2; j++) {
                int o = (w + 4 * j) * 16 + c;
                short8 b = *(const short8*)&wb1[o * 416 + ks * 32 + grp * 8];
                acc[j] = __builtin_amdgcn_mfma_f32_16x16x32_bf16(a, b, acc[j], 0, 0, 0);
            }
        }
        __builtin_amdgcn_s_setprio(0);
        // no barrier: a1s (img region) is disjoint from p2t (p1s region)
#pragma unroll
        for (int j = 0; j < 2; j++) {
            int o = (w + 4 * j) * 16 + c;
            float bias = (o < 120) ? f1b[o] : 0.f;
#pragma unroll
            for (int i = 0; i < 4; i++)
                a1s[(grp * 4 + i) * A1S + o] = f2bf1(fmaxf(acc[j][i] + bias, 0.f));
        }
    }
    __syncthreads();

    // ---- fc2: 120->84 (K=128, 4 steps), N-tiles 0..5, wave w takes w (+4 if w<2) ----
    {
        f32x4 acc[2] = {{0.f,0.f,0.f,0.f},{0.f,0.f,0.f,0.f}};
        const int sb = c * A1S;
#pragma unroll
        for (int ks = 0; ks < 4; ks++) {
            short8 a = *(const short8*)&a1s[sb + ks * 32 + grp * 8];
#pragma unroll
            for (int j = 0; j < 2; j++) {
                int nt = w + 4 * j;
                if (nt < 6) {
                    int o = nt * 16 + c;
                    short8 b = *(const short8*)&wb2[o * 128 + ks * 32 + grp * 8];
                    acc[j] = __builtin_amdgcn_mfma_f32_16x16x32_bf16(a, b, acc[j], 0, 0, 0);
                }
            }
        }
        // no barrier: a2s writes are disjoint from a1s reads (different offsets,
        // and every lane's a1s reads completed before its own a2s writes; cross-
        // wave: fc2 reads a1s rows via lane-private c, writes a2s region only)
#pragma unroll
        for (int j = 0; j < 2; j++) {
            int nt = w + 4 * j;
            if (nt < 6) {
                int o = nt * 16 + c;
                float bias = (o < 84) ? f2b[o] : 0.f;
#pragma unroll
                for (int i = 0; i < 4; i++)
                    a2s[(grp * 4 + i) * A2S + o] = f2bf1(fmaxf(acc[j][i] + bias, 0.f));
            }
        }
    }
    __syncthreads();

    // ---- fc3: 84->64 (K=96, 3 steps), N-tile = w; emb + fused psum ----
    {
        f32x4 acc = {0.f,0.f,0.f,0.f};
        const int sb = c * A2S;
        const int o = w * 16 + c;
#pragma unroll
        for (int ks = 0; ks < 3; ks++) {
            short8 a = *(const short8*)&a2s[sb + ks * 32 + grp * 8];
            short8 b = *(const short8*)&wb3[o * 96 + ks * 32 + grp * 8];
            acc = __builtin_amdgcn_mfma_f32_16x16x32_bf16(a, b, acc, 0, 0, 0);
        }
        const float bias = f3b[o];
        float psum = 0.f;
#pragma unroll
        for (int i = 0; i < 4; i++) {
            float v = acc[i] + bias;
            emb[((size_t)blockIdx.x * 16 + grp * 4 + i) * 64 + o] = v;
            psum += v;
        }
#pragma unroll
        for (int off = 32; off; off >>= 1) psum += __shfl_xor(psum, off);
        if (lane == 0) rsum[w] = psum;
        __syncthreads();
        if (t == 0) part[blockIdx.x] = (rsum[0] + rsum[1]) + (rsum[2] + rsum[3]);
    }
}

// one-shot conversion: FC weights to padded bf16 tiles + conv weight fragments
__global__ __launch_bounds__(256) void prep_weights(
    const float* __restrict__ c1w, const float* __restrict__ c2w,
    const float* __restrict__ f1w, const float* __restrict__ f2w,
    const float* __restrict__ f3w,
    unsigned short* __restrict__ wb1, unsigned short* __restrict__ wb2,
    unsigned short* __restrict__ wb3,
    unsigned short* __restrict__ c1wf, unsigned short* __restrict__ c2wf)
{
    const int t0 = blockIdx.x * 256 + threadIdx.x;
    const int stride = gridDim.x * 256;
    for (int i = t0; i < 128 * 416; i += stride) {
        int o = i / 416, k = i % 416;
        wb1[i] = f2bf((o < 120 && k < 400) ? f1w[o * 400 + k] : 0.f);
    }
    for (int i = t0; i < 96 * 128; i += stride) {
        int o = i / 128, k = i % 128;
        wb2[i] = f2bf((o < 84 && k < 120) ? f2w[o * 120 + k] : 0.f);
    }
    for (int i = t0; i < 64 * 96; i += stride) {
        int o = i / 96, k = i % 96;
        wb3[i] = f2bf((k < 84) ? f3w[o * 84 + k] : 0.f);
    }
    // c1wf[s(5)][off(4)][grp(4)][c(16)][j(8)]
    for (int i = t0; i < 10240; i += stride) {
        int j = i & 7, c = (i >> 3) & 15, grp = (i >> 7) & 3;
        int off = (i >> 9) & 3, s = i >> 11;
        int b = s * 4 + grp;
        int ci = b / 6, kp = b % 6;
        int kx = j - off;
        float v = 0.f;
        if (b < 18 && kx >= 0 && kx <= 4) {
            if (c < 6 && kp <= 4)
                v = c1w[c * 75 + ci * 25 + kp * 5 + kx];
            else if (c >= 8 && c < 14 && kp >= 1)
                v = c1w[(c - 8) * 75 + ci * 25 + (kp - 1) * 5 + kx];
        }
        c1wf[i] = f2bf(v);
    }
    // c2wf[s(8)][off(2)][grp(4)][c(16)][j(8)]
    for (int i = t0; i < 8192; i += stride) {
        int j = i & 7, c = (i >> 3) & 15, grp = (i >> 7) & 3;
        int off = (i >> 9) & 1, s = i >> 10;
        int b = s * 4 + grp;
        int kx = j - off;
        float v = 0.f;
        if (b < 30 && kx >= 0 && kx <= 4) {
            int ci = b / 5, ky = b % 5;
            v = c2w[c * 150 + ci * 25 + ky * 5 + kx];
        }
        c2wf[i] = f2bf(v);
    }
}

// per-row softmax + |softmax - proto|; proto re-reduced per block from the
// 1280 partials (fixed order -> deterministic, identical in every block)
__global__ __launch_bounds__(256) void softmax_abs(float* __restrict__ io,
                                                   const float* __restrict__ part) {
    const int lane = threadIdx.x & 63;
    const int row = (blockIdx.x << 2) + (threadIdx.x >> 6);
    float e = io[(size_t)row * 64 + lane];   // issue early, independent of reduce
    float ps = 0.f;
#pragma unroll
    for (int k = 0; k < 20; k++) ps += part[k * 64 + lane];
#pragma unroll
    for (int off = 32; off; off >>= 1) ps += __shfl_xor(ps, off);
    const float proto = ps / 5.0f;
    float m = e;
#pragma unroll
    for (int off = 32; off; off >>= 1) m = fmaxf(m, __shfl_xor(m, off));
    float p = expf(e - m);
    float s = p;
#pragma unroll
    for (int off = 32; off; off >>= 1) s += __shfl_xor(s, off);
    io[(size_t)row * 64 + lane] = fabsf(p / s - proto);
}

extern "C" void kernel_launch(void* const* d_in, const int* in_sizes, int n_in,
                              void* d_out, int out_size, void* d_ws, size_t ws_size,
                              hipStream_t stream) {
    const float* x   = (const float*)d_in[0];
    const float* c1w = (const float*)d_in[1];
    const float* c1b = (const float*)d_in[2];
    const float* c2w = (const float*)d_in[3];
    const float* c2b = (const float*)d_in[4];
    const float* f1w = (const float*)d_in[5];
    const float* f1b = (const float*)d_in[6];
    const float* f2w = (const float*)d_in[7];
    const float* f2b = (const float*)d_in[8];
    const float* f3w = (const float*)d_in[9];
    const float* f3b = (const float*)d_in[10];
    float* out = (float*)d_out;

    const int N = in_sizes[0] / 3072;                 // 20480
    float* part = (float*)d_ws;                       // N/16 = 1280 floats
    unsigned short* wb1  = (unsigned short*)((char*)d_ws + 8192);  // 128x416
    unsigned short* wb2  = wb1 + 128 * 416;                        // 96x128
    unsigned short* wb3  = wb2 + 96 * 128;                         // 64x96
    unsigned short* c1wf = wb3 + 64 * 96;                          // 10240
    unsigned short* c2wf = c1wf + 10240;                           // 8192

    prep_weights<<<64, 256, 0, stream>>>(c1w, c2w, f1w, f2w, f3w,
                                         wb1, wb2, wb3, c1wf, c2wf);
    conv12fc_mfma<<<N / 16, 256, 0, stream>>>(x, c1wf, c1b, c2wf, c2b,
                                              wb1, f1b, wb2, f2b, wb3, f3b,
                                              out, part);
    softmax_abs<<<N / 4, 256, 0, stream>>>(out, part);
}

// Round 18
// 93.898 us; speedup vs baseline: 1.1354x; 1.1152x over previous
//
#include <hip/hip_runtime.h>
#include <math.h>

typedef __attribute__((ext_vector_type(8))) short short8;
typedef __attribute__((ext_vector_type(4))) float f32x4;
typedef __attribute__((ext_vector_type(4))) unsigned short us4v;

__device__ __forceinline__ unsigned short f2bf(float f) {
    unsigned u = __float_as_uint(f);
    return (unsigned short)((u + 0x7FFFu + ((u >> 16) & 1u)) >> 16);
}
// HW packed f32->bf16 (RNE, same as f2bf): 2 elems in 1 instr; low16 = first arg
__device__ __forceinline__ unsigned cvtpk(float lo, float hi) {
    unsigned r;
    asm("v_cvt_pk_bf16_f32 %0, %1, %2" : "=v"(r) : "v"(lo), "v"(hi));
    return r;
}
__device__ __forceinline__ unsigned short f2bf1(float v) {
    return (unsigned short)(cvtpk(v, 0.f) & 0xffffu);
}
// max with lane (c <-> c+8) partner via DPP row_ror:8 — VALU-only, no LDS pipe
__device__ __forceinline__ float fmax_x8(float v) {
    int s = __builtin_amdgcn_mov_dpp(__float_as_int(v), 0x128, 0xf, 0xf, true);
    return fmaxf(v, __int_as_float(s));
}

#define C1T_SS 3464  // conv1 img LDS elems per sample (96 rows x 36 + 8 tail)
#define C1_RS 36     // conv1 img LDS row stride (32 data + 4 pad)
#define P1R 1176     // p1 record per sample: 84 rows x 14 (stride 14)
#define P2S 424      // fc activation tile row stride (400 + 16 pad + bank spread)
#define A1S 136
#define A2S 104

// Fully fused conv1+pool -> conv2+pool -> fc1 -> fc2 -> fc3 -> emb + psum.
// 16 samples/block. EXACT revert to the R15 measured-best structure (94.6us):
// R16 (8-sample blocks) and R17 (setprio + fc-barrier removal) both regressed
// and are backed out.
__global__ __launch_bounds__(256, 3) void conv12fc_mfma(
    const float* __restrict__ x,
    const unsigned short* __restrict__ c1wf, const float* __restrict__ c1b,
    const unsigned short* __restrict__ c2wf, const float* __restrict__ c2b,
    const unsigned short* __restrict__ wb1, const float* __restrict__ f1b,
    const unsigned short* __restrict__ wb2, const float* __restrict__ f2b,
    const unsigned short* __restrict__ wb3, const float* __restrict__ f3b,
    float* __restrict__ emb, float* __restrict__ part)
{
    __shared__ __align__(16) unsigned short img[2 * C1T_SS];    // 13856 B
    __shared__ __align__(16) unsigned short p1s[16 * P1R + 16]; // 37664 B
    __shared__ float rsum[4];
    const int t = threadIdx.x;
    const int lane = t & 63, w = t >> 6;
    const int grp = lane >> 4, c = lane & 15;
    const int smp = c >> 3, q = c & 7;

    // zero img row pads (2x96 rows, elems 32..35) + sample tails + p1s tail pad
    if (t < 192) {
        int s = t / 96, rr = t - s * 96;
        *(uint2*)&img[s * C1T_SS + rr * C1_RS + 32] = make_uint2(0u, 0u);
    }
    if (t < 2) {
        *(uint4*)&img[t * C1T_SS + 3456] = make_uint4(0u, 0u, 0u, 0u);
        *(uint4*)&p1s[16 * P1R + t * 8] = make_uint4(0u, 0u, 0u, 0u);
    }

    // conv1 weight fragments: ALL 4 x-offset variants
    short8 wf1[5][4];
#pragma unroll
    for (int s = 0; s < 5; s++)
#pragma unroll
        for (int off = 0; off < 4; off++)
            wf1[s][off] = *(const short8*)&c1wf[(((s * 4 + off) * 4 + grp) * 16 + c) * 8];
    int ciA[5], kpA[5];
#pragma unroll
    for (int s = 0; s < 5; s++) {
        int b = s * 4 + grp; if (b > 17) b = 17;   // clamped dup has zero weights
        ciA[s] = b / 6; kpA[s] = b % 6;
    }
    const float bias1 = (c < 6) ? c1b[c] : 0.f;

    const float4* xs4 = (const float4*)(x + (size_t)blockIdx.x * 49152);
    float4 r[6];

    // prologue: load subtile 0 (2 samples = 1536 float4)
#pragma unroll
    for (int k = 0; k < 6; k++) r[k] = xs4[k * 256 + t];

    for (int st = 0; st < 8; st++) {
        // convert + ds_write current subtile (1x per element, cvt_pk)
#pragma unroll
        for (int k = 0; k < 6; k++) {
            int f = k * 256 + t;                  // 0..1535
            int s = (f >= 768) ? 1 : 0;
            int w4 = f - s * 768;
            int ci = w4 >> 8, rem = w4 & 255, y = rem >> 3, xq = rem & 7;
            uint2 pk = make_uint2(cvtpk(r[k].x, r[k].y), cvtpk(r[k].z, r[k].w));
            *(uint2*)&img[s * C1T_SS + (ci * 32 + y) * C1_RS + xq * 4] = pk;
        }
        __syncthreads();

        // issue next subtile's loads (fly under this subtile's compute)
        if (st < 7) {
#pragma unroll
            for (int k = 0; k < 6; k++) r[k] = xs4[(st + 1) * 1536 + k * 256 + t];
        }

        // conv1 compute: 14 py items over 4 waves
        for (int py = w; py < 14; py += 4) {
            f32x4 a00 = {0.f,0.f,0.f,0.f}, a01 = a00, a10 = a00, a11 = a00;
#pragma unroll
            for (int s = 0; s < 5; s++) {
                int e = smp * C1T_SS + (ciA[s] * 32 + py * 2 + kpA[s]) * C1_RS + q * 4;
                union { us4v h[2]; short8 v; } af;
                af.h[0] = *(const us4v*)&img[e];
                af.h[1] = *(const us4v*)&img[e + 4];
                a00 = __builtin_amdgcn_mfma_f32_16x16x32_bf16(af.v, wf1[s][0], a00, 0, 0, 0);
                a01 = __builtin_amdgcn_mfma_f32_16x16x32_bf16(af.v, wf1[s][1], a01, 0, 0, 0);
                a10 = __builtin_amdgcn_mfma_f32_16x16x32_bf16(af.v, wf1[s][2], a10, 0, 0, 0);
                a11 = __builtin_amdgcn_mfma_f32_16x16x32_bf16(af.v, wf1[s][3], a11, 0, 0, 0);
            }
            // pool x-pairs in-lane, y-pair across lane c <-> c+8 (DPP, no LDS)
            f32x4 pe2, po2;
#pragma unroll
            for (int i = 0; i < 4; i++) {
                pe2[i] = fmax_x8(fmaxf(a00[i], a01[i]));
                po2[i] = fmax_x8(fmaxf(a10[i], a11[i]));
            }
            if (c < 6) {
#pragma unroll
                for (int i = 0; i < 4; i++) {
                    int m = grp * 4 + i;           // D row: sample = m>>3, quad = m&7
                    int qo = m & 7;
                    if (qo < 7) {
                        int sm = m >> 3;
                        float v0 = fmaxf(pe2[i] + bias1, 0.f);
                        float v1 = fmaxf(po2[i] + bias1, 0.f);
                        *(unsigned*)&p1s[(2 * st + sm) * P1R + (c * 14 + py) * 14 + qo * 2]
                            = cvtpk(v0, v1);
                    }
                }
            }
        }
        __syncthreads();   // img reads done before next convert; p1s subtile written
    }

    // ---- conv2 phase (wf2 loaded after conv1 regs die) ----
    short8 wf2[8][2];
#pragma unroll
    for (int s = 0; s < 8; s++)
#pragma unroll
        for (int off = 0; off < 2; off++)
            wf2[s][off] = *(const short8*)&c2wf[(((s * 2 + off) * 4 + grp) * 16 + c) * 8];
    int ciB[8], kyB[8];
#pragma unroll
    for (int s = 0; s < 8; s++) {
        int b = s * 4 + grp; if (b > 29) b = 29;   // clamped dup has zero weights
        ciB[s] = b / 5; kyB[s] = b % 5;
    }
    const float bias2 = c2b[c];

    // conv2 compute -> per-lane register buffer (statically indexed)
    unsigned pkbuf[7][2];
#pragma unroll
    for (int j = 0; j < 7; j++) {
        const int item = w + j * 4;
        if (item < 25) {
            const int py = item / 5, px = item % 5;
            f32x4 a00 = {0.f,0.f,0.f,0.f}, a01 = a00, a10 = a00, a11 = a00;
#pragma unroll
            for (int s = 0; s < 8; s++) {
                int rbase = ciB[s] * 14 + kyB[s] + py * 2;
#pragma unroll
                for (int yo = 0; yo < 2; yo++) {
                    int e = c * P1R + (rbase + yo) * 14 + px * 2;
                    union { unsigned u[4]; short8 v; } af;
                    af.u[0] = *(const unsigned*)&p1s[e];
                    af.u[1] = *(const unsigned*)&p1s[e + 2];
                    af.u[2] = *(const unsigned*)&p1s[e + 4];
                    af.u[3] = *(const unsigned*)&p1s[e + 6];
                    if (yo == 0) {
                        a00 = __builtin_amdgcn_mfma_f32_16x16x32_bf16(af.v, wf2[s][0], a00, 0, 0, 0);
                        a01 = __builtin_amdgcn_mfma_f32_16x16x32_bf16(af.v, wf2[s][1], a01, 0, 0, 0);
                    } else {
                        a10 = __builtin_amdgcn_mfma_f32_16x16x32_bf16(af.v, wf2[s][0], a10, 0, 0, 0);
                        a11 = __builtin_amdgcn_mfma_f32_16x16x32_bf16(af.v, wf2[s][1], a11, 0, 0, 0);
                    }
                }
            }
            float v0 = fmaxf(fmaxf(fmaxf(a00[0], a01[0]), fmaxf(a10[0], a11[0])) + bias2, 0.f);
            float v1 = fmaxf(fmaxf(fmaxf(a00[1], a01[1]), fmaxf(a10[1], a11[1])) + bias2, 0.f);
            float v2 = fmaxf(fmaxf(fmaxf(a00[2], a01[2]), fmaxf(a10[2], a11[2])) + bias2, 0.f);
            float v3 = fmaxf(fmaxf(fmaxf(a00[3], a01[3]), fmaxf(a10[3], a11[3])) + bias2, 0.f);
            pkbuf[j][0] = cvtpk(v0, v1);
            pkbuf[j][1] = cvtpk(v2, v3);
        }
    }
    __syncthreads();   // all p1s reads complete -> safe to overlay fc tile

    // scatter into fc activation tile [16][424] (overlaid on p1s) + zero K-pad
    unsigned short* p2t = p1s;
#pragma unroll
    for (int j = 0; j < 7; j++) {
        const int item = w + j * 4;
        if (item < 25) {
#pragma unroll
            for (int i = 0; i < 4; i++) {
                unsigned v = pkbuf[j][i >> 1] >> ((i & 1) * 16);
                p2t[(grp * 4 + i) * P2S + c * 25 + item] = (unsigned short)v;
            }
        }
    }
    if (t < 32) {
        int s = t >> 1, h = t & 1;
        *(uint4*)&p2t[s * P2S + 400 + h * 8] = make_uint4(0u, 0u, 0u, 0u);
    }
    __syncthreads();

    // ---- fc1: 400->120 (K=416, 13 steps), N-tiles 0..7, wave w takes w, w+4 ----
    unsigned short* a1s = img;              // img is dead; 16x136 = 4352 B
    unsigned short* a2s = img + 16 * A1S;   // 16x104 = 3328 B
    {
        f32x4 acc[2] = {{0.f,0.f,0.f,0.f},{0.f,0.f,0.f,0.f}};
        const int sb = c * P2S;
#pragma unroll
        for (int ks = 0; ks < 13; ks++) {
            short8 a = *(const short8*)&p2t[sb + ks * 32 + grp * 8];
#pragma unroll
            for (int j = 0; j < 2; j++) {
                int o = (w + 4 * j) * 16 + c;
                short8 b = *(const short8*)&wb1[o * 416 + ks * 32 + grp * 8];
                acc[j] = __builtin_amdgcn_mfma_f32_16x16x32_bf16(a, b, acc[j], 0, 0, 0);
            }
        }
        __syncthreads();
#pragma unroll
        for (int j = 0; j < 2; j++) {
            int o = (w + 4 * j) * 16 + c;
            float bias = (o < 120) ? f1b[o] : 0.f;
#pragma unroll
            for (int i = 0; i < 4; i++)
                a1s[(grp * 4 + i) * A1S + o] = f2bf1(fmaxf(acc[j][i] + bias, 0.f));
        }
    }
    __syncthreads();

    // ---- fc2: 120->84 (K=128, 4 steps), N-tiles 0..5, wave w takes w (+4 if w<2) ----
    {
        f32x4 acc[2] = {{0.f,0.f,0.f,0.f},{0.f,0.f,0.f,0.f}};
        const int sb = c * A1S;
#pragma unroll
        for (int ks = 0; ks < 4; ks++) {
            short8 a = *(const short8*)&a1s[sb + ks * 32 + grp * 8];
#pragma unroll
            for (int j = 0; j < 2; j++) {
                int nt = w + 4 * j;
                if (nt < 6) {
                    int o = nt * 16 + c;
                    short8 b = *(const short8*)&wb2[o * 128 + ks * 32 + grp * 8];
                    acc[j] = __builtin_amdgcn_mfma_f32_16x16x32_bf16(a, b, acc[j], 0, 0, 0);
                }
            }
        }
        __syncthreads();
#pragma unroll
        for (int j = 0; j < 2; j++) {
            int nt = w + 4 * j;
            if (nt < 6) {
                int o = nt * 16 + c;
                float bias = (o < 84) ? f2b[o] : 0.f;
#pragma unroll
                for (int i = 0; i < 4; i++)
                    a2s[(grp * 4 + i) * A2S + o] = f2bf1(fmaxf(acc[j][i] + bias, 0.f));
            }
        }
    }
    __syncthreads();

    // ---- fc3: 84->64 (K=96, 3 steps), N-tile = w; emb + fused psum ----
    {
        f32x4 acc = {0.f,0.f,0.f,0.f};
        const int sb = c * A2S;
        const int o = w * 16 + c;
#pragma unroll
        for (int ks = 0; ks < 3; ks++) {
            short8 a = *(const short8*)&a2s[sb + ks * 32 + grp * 8];
            short8 b = *(const short8*)&wb3[o * 96 + ks * 32 + grp * 8];
            acc = __builtin_amdgcn_mfma_f32_16x16x32_bf16(a, b, acc, 0, 0, 0);
        }
        const float bias = f3b[o];
        float psum = 0.f;
#pragma unroll
        for (int i = 0; i < 4; i++) {
            float v = acc[i] + bias;
            emb[((size_t)blockIdx.x * 16 + grp * 4 + i) * 64 + o] = v;
            psum += v;
        }
#pragma unroll
        for (int off = 32; off; off >>= 1) psum += __shfl_xor(psum, off);
        if (lane == 0) rsum[w] = psum;
        __syncthreads();
        if (t == 0) part[blockIdx.x] = (rsum[0] + rsum[1]) + (rsum[2] + rsum[3]);
    }
}

// one-shot conversion: FC weights to padded bf16 tiles + conv weight fragments
__global__ __launch_bounds__(256) void prep_weights(
    const float* __restrict__ c1w, const float* __restrict__ c2w,
    const float* __restrict__ f1w, const float* __restrict__ f2w,
    const float* __restrict__ f3w,
    unsigned short* __restrict__ wb1, unsigned short* __restrict__ wb2,
    unsigned short* __restrict__ wb3,
    unsigned short* __restrict__ c1wf, unsigned short* __restrict__ c2wf)
{
    const int t0 = blockIdx.x * 256 + threadIdx.x;
    const int stride = gridDim.x * 256;
    for (int i = t0; i < 128 * 416; i += stride) {
        int o = i / 416, k = i % 416;
        wb1[i] = f2bf((o < 120 && k < 400) ? f1w[o * 400 + k] : 0.f);
    }
    for (int i = t0; i < 96 * 128; i += stride) {
        int o = i / 128, k = i % 128;
        wb2[i] = f2bf((o < 84 && k < 120) ? f2w[o * 120 + k] : 0.f);
    }
    for (int i = t0; i < 64 * 96; i += stride) {
        int o = i / 96, k = i % 96;
        wb3[i] = f2bf((k < 84) ? f3w[o * 84 + k] : 0.f);
    }
    // c1wf[s(5)][off(4)][grp(4)][c(16)][j(8)]
    for (int i = t0; i < 10240; i += stride) {
        int j = i & 7, c = (i >> 3) & 15, grp = (i >> 7) & 3;
        int off = (i >> 9) & 3, s = i >> 11;
        int b = s * 4 + grp;
        int ci = b / 6, kp = b % 6;
        int kx = j - off;
        float v = 0.f;
        if (b < 18 && kx >= 0 && kx <= 4) {
            if (c < 6 && kp <= 4)
                v = c1w[c * 75 + ci * 25 + kp * 5 + kx];
            else if (c >= 8 && c < 14 && kp >= 1)
                v = c1w[(c - 8) * 75 + ci * 25 + (kp - 1) * 5 + kx];
        }
        c1wf[i] = f2bf(v);
    }
    // c2wf[s(8)][off(2)][grp(4)][c(16)][j(8)]
    for (int i = t0; i < 8192; i += stride) {
        int j = i & 7, c = (i >> 3) & 15, grp = (i >> 7) & 3;
        int off = (i >> 9) & 1, s = i >> 10;
        int b = s * 4 + grp;
        int kx = j - off;
        float v = 0.f;
        if (b < 30 && kx >= 0 && kx <= 4) {
            int ci = b / 5, ky = b % 5;
            v = c2w[c * 150 + ci * 25 + ky * 5 + kx];
        }
        c2wf[i] = f2bf(v);
    }
}

// per-row softmax + |softmax - proto|; proto re-reduced per block from the
// 1280 partials (fixed order -> deterministic, identical in every block)
__global__ __launch_bounds__(256) void softmax_abs(float* __restrict__ io,
                                                   const float* __restrict__ part) {
    const int lane = threadIdx.x & 63;
    const int row = (blockIdx.x << 2) + (threadIdx.x >> 6);
    float e = io[(size_t)row * 64 + lane];   // issue early, independent of reduce
    float ps = 0.f;
#pragma unroll
    for (int k = 0; k < 20; k++) ps += part[k * 64 + lane];
#pragma unroll
    for (int off = 32; off; off >>= 1) ps += __shfl_xor(ps, off);
    const float proto = ps / 5.0f;
    float m = e;
#pragma unroll
    for (int off = 32; off; off >>= 1) m = fmaxf(m, __shfl_xor(m, off));
    float p = expf(e - m);
    float s = p;
#pragma unroll
    for (int off = 32; off; off >>= 1) s += __shfl_xor(s, off);
    io[(size_t)row * 64 + lane] = fabsf(p / s - proto);
}

extern "C" void kernel_launch(void* const* d_in, const int* in_sizes, int n_in,
                              void* d_out, int out_size, void* d_ws, size_t ws_size,
                              hipStream_t stream) {
    const float* x   = (const float*)d_in[0];
    const float* c1w = (const float*)d_in[1];
    const float* c1b = (const float*)d_in[2];
    const float* c2w = (const float*)d_in[3];
    const float* c2b = (const float*)d_in[4];
    const float* f1w = (const float*)d_in[5];
    const float* f1b = (const float*)d_in[6];
    const float* f2w = (const float*)d_in[7];
    const float* f2b = (const float*)d_in[8];
    const float* f3w = (const float*)d_in[9];
    const float* f3b = (const float*)d_in[10];
    float* out = (float*)d_out;

    const int N = in_sizes[0] / 3072;                 // 20480
    float* part = (float*)d_ws;                       // N/16 = 1280 floats
    unsigned short* wb1  = (unsigned short*)((char*)d_ws + 8192);  // 128x416
    unsigned short* wb2  = wb1 + 128 * 416;                        // 96x128
    unsigned short* wb3  = wb2 + 96 * 128;                         // 64x96
    unsigned short* c1wf = wb3 + 64 * 96;                          // 10240
    unsigned short* c2wf = c1wf + 10240;                           // 8192

    prep_weights<<<64, 256, 0, stream>>>(c1w, c2w, f1w, f2w, f3w,
                                         wb1, wb2, wb3, c1wf, c2wf);
    conv12fc_mfma<<<N / 16, 256, 0, stream>>>(x, c1wf, c1b, c2wf, c2b,
                                              wb1, f1b, wb2, f2b, wb3, f3b,
                                              out, part);
    softmax_abs<<<N / 4, 256, 0, stream>>>(out, part);
}